// Round 1
// baseline (71.991 us; speedup 1.0000x reference)
//
#include <hip/hip_runtime.h>
#include <math.h>

// Problem constants (from reference setup_inputs)
#define D 128
#define BGRAPHS 256
#define NH 6144
#define NT 6144
#define EH 10240
#define ET 10240
// rows per graph: NH/B = 24 (nodes), EH/B = 40 (line graph)

// ---------------- workspace layout (floats) ----------------
// xh1 @ 0          (NH*128)
// xh2 @ 786432
// xt1 @ 1572864
// xt2 @ 2359296
// lh1 @ 3145728    (EH*128)
// lh2 @ 4456448
// lt1 @ 5767168
// lt2 @ 7077888
// total 8388608 floats = 32 MiB

struct ProjJobs {
    const float* X[8];
    const float* W[8];
    const float* Bb[8];
    float* Y[8];
    int N[8];
};

// Y[r,c] = bias[c] + sum_k X[r,k] * W[c,k]   (i.e. x @ W^T + b)
// block: 256 threads, 32 rows x 128 cols per block, 4x4 register tile/thread
__global__ __launch_bounds__(256) void proj_kernel(ProjJobs jobs) {
    const int job = blockIdx.y;
    const int row0 = blockIdx.x * 32;
    if (row0 >= jobs.N[job]) return;
    const float* __restrict__ X = jobs.X[job];
    const float* __restrict__ W = jobs.W[job];
    const float* __restrict__ bias = jobs.Bb[job];
    float* __restrict__ Y = jobs.Y[job];

    __shared__ float Xt[32][132];    // [row][k], padded
    __shared__ float WtT[32][132];   // [kk][c], padded (transposed W k-tile)

    const int tid = threadIdx.x;

    // stage X rows (32 rows x 128 floats = 1024 float4)
    {
        for (int e = tid; e < 32 * 32; e += 256) {
            int r = e >> 5, c4 = e & 31;
            float4 v = *reinterpret_cast<const float4*>(&X[(row0 + r) * D + c4 * 4]);
            *reinterpret_cast<float4*>(&Xt[r][c4 * 4]) = v;
        }
    }

    float acc[4][4];
#pragma unroll
    for (int i = 0; i < 4; ++i)
#pragma unroll
        for (int j = 0; j < 4; ++j) acc[i][j] = 0.f;

    const int c0 = (tid & 31) * 4;
    const int r0 = (tid >> 5) * 4;

    for (int k0 = 0; k0 < D; k0 += 32) {
        __syncthreads();
        // stage WtT[kk][c] = W[c][k0+kk]  (coalesced global read)
        for (int e = tid; e < 128 * 32; e += 256) {
            int c = e >> 5, kk = e & 31;
            WtT[kk][c] = W[c * D + k0 + kk];
        }
        __syncthreads();
#pragma unroll
        for (int kk4 = 0; kk4 < 8; ++kk4) {
            float4 xv[4];
#pragma unroll
            for (int i = 0; i < 4; ++i)
                xv[i] = *reinterpret_cast<const float4*>(&Xt[r0 + i][k0 + kk4 * 4]);
#pragma unroll
            for (int kj = 0; kj < 4; ++kj) {
                float4 wv = *reinterpret_cast<const float4*>(&WtT[kk4 * 4 + kj][c0]);
#pragma unroll
                for (int i = 0; i < 4; ++i) {
                    float xs = (kj == 0) ? xv[i].x : (kj == 1) ? xv[i].y
                             : (kj == 2) ? xv[i].z : xv[i].w;
                    acc[i][0] += xs * wv.x;
                    acc[i][1] += xs * wv.y;
                    acc[i][2] += xs * wv.z;
                    acc[i][3] += xs * wv.w;
                }
            }
        }
    }

    float4 bv = *reinterpret_cast<const float4*>(&bias[c0]);
#pragma unroll
    for (int i = 0; i < 4; ++i) {
        float4 o;
        o.x = acc[i][0] + bv.x;
        o.y = acc[i][1] + bv.y;
        o.z = acc[i][2] + bv.z;
        o.w = acc[i][3] + bv.w;
        *reinterpret_cast<float4*>(&Y[(row0 + r0 + i) * D + c0]) = o;
    }
}

// One block per (graph, level). Computes block-diagonal alpha, row/col means,
// per-graph softmax, and p-weighted sums of original x rows.
__global__ __launch_bounds__(256) void attn_kernel(
    const float* __restrict__ xnh, const float* __restrict__ xnt,
    const float* __restrict__ xlh, const float* __restrict__ xlt,
    const float* __restrict__ ws, float* __restrict__ out)
{
    const int level = blockIdx.y;
    const int g = blockIdx.x;
    const int R = (level == 0) ? 24 : 40;   // rows per graph, both sides

    const float *xh, *xt, *xh1, *xh2, *xt1, *xt2;
    float *out_sh, *out_st;
    if (level == 0) {
        xh = xnh; xt = xnt;
        xh1 = ws + 0;       xh2 = ws + 786432;
        xt1 = ws + 1572864; xt2 = ws + 2359296;
        out_sh = out + 0;     out_st = out + 32768;
    } else {
        xh = xlh; xt = xlt;
        xh1 = ws + 3145728; xh2 = ws + 4456448;
        xt1 = ws + 5767168; xt2 = ws + 7077888;
        out_sh = out + 65536; out_st = out + 98304;
    }
    const int h0 = g * R, t0 = g * R;

    __shared__ float t1b[40][132], t2b[40][132];
    __shared__ float h1c[8][132], h2c[8][132];
    __shared__ float alph[8][44];
    __shared__ float colsum[40], rowsum[40];
    __shared__ float p_t[40], p_h[40];

    const int tid = threadIdx.x;

    // stage xt1/xt2 blocks (R rows x 128 floats each)
    for (int e = tid; e < R * 32; e += 256) {
        int r = e >> 5, c4 = e & 31;
        float4 v1 = *reinterpret_cast<const float4*>(&xt1[(t0 + r) * D + c4 * 4]);
        float4 v2 = *reinterpret_cast<const float4*>(&xt2[(t0 + r) * D + c4 * 4]);
        *reinterpret_cast<float4*>(&t1b[r][c4 * 4]) = v1;
        *reinterpret_cast<float4*>(&t2b[r][c4 * 4]) = v2;
    }
    if (tid < 40) colsum[tid] = 0.f;
    __syncthreads();

    for (int ic0 = 0; ic0 < R; ic0 += 8) {
        // stage 8 h-rows
        for (int e = tid; e < 8 * 32; e += 256) {
            int r = e >> 5, c4 = e & 31;
            float4 v1 = *reinterpret_cast<const float4*>(&xh1[(h0 + ic0 + r) * D + c4 * 4]);
            float4 v2 = *reinterpret_cast<const float4*>(&xh2[(h0 + ic0 + r) * D + c4 * 4]);
            *reinterpret_cast<float4*>(&h1c[r][c4 * 4]) = v1;
            *reinterpret_cast<float4*>(&h2c[r][c4 * 4]) = v2;
        }
        __syncthreads();

        // alpha entries for this 8 x R chunk
        for (int p = tid; p < 8 * R; p += 256) {
            int i = p / R, j = p % R;
            float s = 0.f;
            for (int k4 = 0; k4 < 32; ++k4) {
                float4 a1 = *reinterpret_cast<const float4*>(&h1c[i][k4 * 4]);
                float4 b1 = *reinterpret_cast<const float4*>(&t1b[j][k4 * 4]);
                float4 a2 = *reinterpret_cast<const float4*>(&h2c[i][k4 * 4]);
                float4 b2 = *reinterpret_cast<const float4*>(&t2b[j][k4 * 4]);
                s += a1.x * b1.x + a1.y * b1.y + a1.z * b1.z + a1.w * b1.w
                   + a2.x * b2.x + a2.y * b2.y + a2.z * b2.z + a2.w * b2.w;
            }
            alph[i][j] = tanhf(s);
        }
        __syncthreads();

        // accumulate row/col sums
        if (tid < R) {
            float cs = 0.f;
#pragma unroll
            for (int i = 0; i < 8; ++i) cs += alph[i][tid];
            colsum[tid] += cs;
        } else if (tid >= 64 && tid < 72) {
            int i = tid - 64;
            float rs = 0.f;
            for (int j = 0; j < R; ++j) rs += alph[i][j];
            rowsum[ic0 + i] = rs;
        }
        __syncthreads();
    }

    // per-graph softmax: wave0 -> p_t (from colsum / cnt_h), wave1 -> p_h
    const int wave = tid >> 6, lane = tid & 63;
    if (wave < 2) {
        const float* src = (wave == 0) ? colsum : rowsum;
        float* dst = (wave == 0) ? p_t : p_h;
        float v = (lane < R) ? src[lane] / (float)R : -INFINITY;
        float m = v;
        for (int o = 32; o; o >>= 1) m = fmaxf(m, __shfl_xor(m, o, 64));
        float e = (lane < R) ? expf(v - m) : 0.f;
        float ssum = e;
        for (int o = 32; o; o >>= 1) ssum += __shfl_xor(ssum, o, 64);
        if (lane < R) dst[lane] = e / ssum;
    }
    __syncthreads();

    // outputs: threads 0..127 -> s_t column c, threads 128..255 -> s_h column c
    if (tid < 128) {
        int c = tid;
        float acc = 0.f;
        for (int j = 0; j < R; ++j) acc += p_t[j] * xt[(t0 + j) * D + c];
        out_st[g * D + c] = acc;
    } else {
        int c = tid - 128;
        float acc = 0.f;
        for (int i = 0; i < R; ++i) acc += p_h[i] * xh[(h0 + i) * D + c];
        out_sh[g * D + c] = acc;
    }
}

extern "C" void kernel_launch(void* const* d_in, const int* in_sizes, int n_in,
                              void* d_out, int out_size, void* d_ws, size_t ws_size,
                              hipStream_t stream) {
    const float* xnh  = (const float*)d_in[0];
    const float* xnt  = (const float*)d_in[1];
    const float* xlh  = (const float*)d_in[2];
    const float* xlt  = (const float*)d_in[3];
    const float* Wh_w  = (const float*)d_in[4];
    const float* Wh_b  = (const float*)d_in[5];
    const float* Wt_w  = (const float*)d_in[6];
    const float* Wt_b  = (const float*)d_in[7];
    const float* Whl_w = (const float*)d_in[8];
    const float* Whl_b = (const float*)d_in[9];
    const float* Wtl_w = (const float*)d_in[10];
    const float* Wtl_b = (const float*)d_in[11];

    float* ws  = (float*)d_ws;
    float* out = (float*)d_out;

    ProjJobs jobs;
    // node level: xh1 = xh@Wh^T+bh ; xh2 = xh@Wt^T+bt ; xt1 = xt@Wt^T+bt ; xt2 = xt@Wh^T+bh
    jobs.X[0] = xnh; jobs.W[0] = Wh_w; jobs.Bb[0] = Wh_b; jobs.Y[0] = ws + 0;       jobs.N[0] = NH;
    jobs.X[1] = xnh; jobs.W[1] = Wt_w; jobs.Bb[1] = Wt_b; jobs.Y[1] = ws + 786432;  jobs.N[1] = NH;
    jobs.X[2] = xnt; jobs.W[2] = Wt_w; jobs.Bb[2] = Wt_b; jobs.Y[2] = ws + 1572864; jobs.N[2] = NT;
    jobs.X[3] = xnt; jobs.W[3] = Wh_w; jobs.Bb[3] = Wh_b; jobs.Y[3] = ws + 2359296; jobs.N[3] = NT;
    // line level
    jobs.X[4] = xlh; jobs.W[4] = Whl_w; jobs.Bb[4] = Whl_b; jobs.Y[4] = ws + 3145728; jobs.N[4] = EH;
    jobs.X[5] = xlh; jobs.W[5] = Wtl_w; jobs.Bb[5] = Wtl_b; jobs.Y[5] = ws + 4456448; jobs.N[5] = EH;
    jobs.X[6] = xlt; jobs.W[6] = Wtl_w; jobs.Bb[6] = Wtl_b; jobs.Y[6] = ws + 5767168; jobs.N[6] = ET;
    jobs.X[7] = xlt; jobs.W[7] = Whl_w; jobs.Bb[7] = Whl_b; jobs.Y[7] = ws + 7077888; jobs.N[7] = ET;

    // grid.x = max(N)/32 = 10240/32 = 320; small jobs early-exit
    proj_kernel<<<dim3(320, 8), 256, 0, stream>>>(jobs);
    attn_kernel<<<dim3(BGRAPHS, 2), 256, 0, stream>>>(xnh, xnt, xlh, xlt, ws, out);
}

// Round 2
// 43.259 us; speedup vs baseline: 1.6642x; 1.6642x over previous
//
#include <hip/hip_runtime.h>
#include <math.h>

// Problem constants
#define D 128
#define BGRAPHS 256
// rows/graph: node 24, line 40
// ws layout (bf16/ushort elements), total exactly 32 MiB:
//  xh1 hi@0        lo@786432
//  xh2 hi@1572864  lo@2359296
//  xt1 hi@3145728  lo@3932160
//  xt2 hi@4718592  lo@5505024
//  lh1 hi@6291456  lo@7602176
//  lh2 hi@8912896  lo@10223616
//  lt1 hi@11534336 lo@12845056
//  lt2 hi@14155776 lo@15466496   end 16777216 elems = 32 MiB

typedef float f32x4 __attribute__((ext_vector_type(4)));
typedef short s16x8 __attribute__((ext_vector_type(8)));

__device__ __forceinline__ unsigned bf16h(float f) {
    unsigned u = __float_as_uint(f);
    return (u + 0x7fffu + ((u >> 16) & 1u)) >> 16;   // RNE
}
__device__ __forceinline__ float bf16tof(unsigned h) { return __uint_as_float(h << 16); }

struct ProjArgs {
    const float* X[8];
    const float* W[8];
    const float* Bv[8];
    unsigned short* Yhi[8];
    unsigned short* Ylo[8];
};

// One block = 256 rows of one job. 512 threads = 8 waves, wave does 32 rows x 128 cols.
// Computes C = W * X^T via mfma_f32_16x16x32_bf16 with split-bf16 3-pass.
__global__ __launch_bounds__(512) void proj_kernel(ProjArgs A) {
    __shared__ unsigned short whi[16384];
    __shared__ unsigned short wlo[16384];

    const int b = blockIdx.x;
    int job, r0b;
    if (b < 96) { job = b / 24; r0b = (b - job * 24) * 256; }
    else { int c = b - 96; int j4 = c / 40; job = 4 + j4; r0b = (c - j4 * 40) * 256; }

    const float* __restrict__ X = A.X[job];
    const float* __restrict__ W = A.W[job];
    const float* __restrict__ Bv = A.Bv[job];
    unsigned short* __restrict__ Yhi = A.Yhi[job];
    unsigned short* __restrict__ Ylo = A.Ylo[job];

    const int tid = threadIdx.x;

    // ---- stage W as hi/lo bf16 in LDS, XOR-swizzled (elem col ^= (row&7)<<3) ----
#pragma unroll
    for (int it = 0; it < 8; ++it) {
        int q = tid + it * 512;          // float4 index 0..4095
        int e = q * 4;
        int row = e >> 7, col = e & 127;
        float4 v = *reinterpret_cast<const float4*>(&W[e]);
        unsigned h0 = bf16h(v.x), h1 = bf16h(v.y), h2 = bf16h(v.z), h3 = bf16h(v.w);
        unsigned l0 = bf16h(v.x - bf16tof(h0));
        unsigned l1 = bf16h(v.y - bf16tof(h1));
        unsigned l2 = bf16h(v.z - bf16tof(h2));
        unsigned l3 = bf16h(v.w - bf16tof(h3));
        int o = row * 128 + (col ^ ((row & 7) << 3));
        *reinterpret_cast<ushort4*>(&whi[o]) =
            make_ushort4((unsigned short)h0, (unsigned short)h1, (unsigned short)h2, (unsigned short)h3);
        *reinterpret_cast<ushort4*>(&wlo[o]) =
            make_ushort4((unsigned short)l0, (unsigned short)l1, (unsigned short)l2, (unsigned short)l3);
    }
    __syncthreads();

    const int wv = tid >> 6;
    const int l = tid & 63;
    const int lm = l & 15, lq = l >> 4;
    const int rowbase = r0b + wv * 32;

    // ---- load X fragments (B operand: B[k][m] = X[m][k]), split hi/lo ----
    s16x8 bxh[2][4], bxl[2][4];
#pragma unroll
    for (int rt = 0; rt < 2; ++rt) {
        const float* xr = X + (rowbase + rt * 16 + lm) * D;
#pragma unroll
        for (int ks = 0; ks < 4; ++ks) {
            int k0 = ks * 32 + lq * 8;
            float4 va = *reinterpret_cast<const float4*>(&xr[k0]);
            float4 vb = *reinterpret_cast<const float4*>(&xr[k0 + 4]);
            float f[8] = {va.x, va.y, va.z, va.w, vb.x, vb.y, vb.z, vb.w};
            s16x8 hv, lv;
#pragma unroll
            for (int e = 0; e < 8; ++e) {
                unsigned h = bf16h(f[e]);
                hv[e] = (short)h;
                lv[e] = (short)bf16h(f[e] - bf16tof(h));
            }
            bxh[rt][ks] = hv;
            bxl[rt][ks] = lv;
        }
    }

    // ---- K-loop: A = W rows from LDS, 3-pass split MFMA ----
#pragma unroll
    for (int ct = 0; ct < 8; ++ct) {
        f32x4 acc0 = {0.f, 0.f, 0.f, 0.f}, acc1 = {0.f, 0.f, 0.f, 0.f};
        const int n = ct * 16 + lm;
        const int swz = (n & 7) << 3;
        const int rowoff = n * 128;
#pragma unroll
        for (int ks = 0; ks < 4; ++ks) {
            int k0 = ks * 32 + lq * 8;
            int off = rowoff + (k0 ^ swz);
            s16x8 ah = *reinterpret_cast<const s16x8*>(&whi[off]);
            s16x8 al = *reinterpret_cast<const s16x8*>(&wlo[off]);
            acc0 = __builtin_amdgcn_mfma_f32_16x16x32_bf16(ah, bxh[0][ks], acc0, 0, 0, 0);
            acc0 = __builtin_amdgcn_mfma_f32_16x16x32_bf16(ah, bxl[0][ks], acc0, 0, 0, 0);
            acc0 = __builtin_amdgcn_mfma_f32_16x16x32_bf16(al, bxh[0][ks], acc0, 0, 0, 0);
            acc1 = __builtin_amdgcn_mfma_f32_16x16x32_bf16(ah, bxh[1][ks], acc1, 0, 0, 0);
            acc1 = __builtin_amdgcn_mfma_f32_16x16x32_bf16(ah, bxl[1][ks], acc1, 0, 0, 0);
            acc1 = __builtin_amdgcn_mfma_f32_16x16x32_bf16(al, bxh[1][ks], acc1, 0, 0, 0);
        }
        // epilogue: lane holds Y[m = rowbase+rt*16+lm][n = ct*16+lq*4 + reg]
        float4 bias4 = *reinterpret_cast<const float4*>(&Bv[ct * 16 + lq * 4]);
#pragma unroll
        for (int rt = 0; rt < 2; ++rt) {
            f32x4 acc = rt ? acc1 : acc0;
            int m = rowbase + rt * 16 + lm;
            int n0 = ct * 16 + lq * 4;
            float y0 = acc[0] + bias4.x, y1 = acc[1] + bias4.y;
            float y2 = acc[2] + bias4.z, y3 = acc[3] + bias4.w;
            unsigned h0 = bf16h(y0), h1 = bf16h(y1), h2 = bf16h(y2), h3 = bf16h(y3);
            ushort4 ho = make_ushort4((unsigned short)h0, (unsigned short)h1,
                                      (unsigned short)h2, (unsigned short)h3);
            ushort4 lo4 = make_ushort4((unsigned short)bf16h(y0 - bf16tof(h0)),
                                       (unsigned short)bf16h(y1 - bf16tof(h1)),
                                       (unsigned short)bf16h(y2 - bf16tof(h2)),
                                       (unsigned short)bf16h(y3 - bf16tof(h3)));
            *reinterpret_cast<ushort4*>(&Yhi[m * 128 + n0]) = ho;
            *reinterpret_cast<ushort4*>(&Ylo[m * 128 + n0]) = lo4;
        }
    }
}

// One wave per (graph, level): block-diagonal alpha via MFMA, fragment-layout
// reductions, softmax, p-weighted sums of original x.
template <int LEVEL>
__device__ __forceinline__ void attn_body(
    int g, const float* __restrict__ xh, const float* __restrict__ xt,
    const unsigned short* __restrict__ ws, float* __restrict__ osh,
    float* __restrict__ ost, float* PT, float* PH)
{
    constexpr int R = (LEVEL == 0) ? 24 : 40;
    constexpr int TM = (LEVEL == 0) ? 2 : 3;
    constexpr int NODE_E = 786432, LINE_E = 1310720;

    const unsigned short *h1, *h1l, *h2, *h2l, *t1, *t1l, *t2, *t2l;
    if (LEVEL == 0) {
        h1 = ws + 0;        h1l = h1 + NODE_E;
        h2 = ws + 1572864;  h2l = h2 + NODE_E;
        t1 = ws + 3145728;  t1l = t1 + NODE_E;
        t2 = ws + 4718592;  t2l = t2 + NODE_E;
    } else {
        h1 = ws + 6291456;  h1l = h1 + LINE_E;
        h2 = ws + 8912896;  h2l = h2 + LINE_E;
        t1 = ws + 11534336; t1l = t1 + LINE_E;
        t2 = ws + 14155776; t2l = t2 + LINE_E;
    }
    const int l = threadIdx.x & 63;
    const int lm = l & 15, lq = l >> 4;
    const int base = g * R;

    const f32x4 zf = {0.f, 0.f, 0.f, 0.f};
    f32x4 acc[TM][TM];
#pragma unroll
    for (int i = 0; i < TM; ++i)
#pragma unroll
        for (int j = 0; j < TM; ++j) acc[i][j] = zf;

    const s16x8 z8 = {0, 0, 0, 0, 0, 0, 0, 0};
#pragma unroll
    for (int ks = 0; ks < 4; ++ks) {
        const int k0 = ks * 32 + lq * 8;
        s16x8 a1h[TM], a1l[TM], a2h[TM], a2l[TM];
        s16x8 b1h[TM], b1l[TM], b2h[TM], b2l[TM];
#pragma unroll
        for (int ti = 0; ti < TM; ++ti) {
            int i = ti * 16 + lm;
            bool v = (i < R);
            int ic = v ? i : (R - 1);          // clamp: safe address, then select 0
            int off = (base + ic) * D + k0;
            s16x8 x1h = *reinterpret_cast<const s16x8*>(&h1[off]);
            s16x8 x1l = *reinterpret_cast<const s16x8*>(&h1l[off]);
            s16x8 x2h = *reinterpret_cast<const s16x8*>(&h2[off]);
            s16x8 x2l = *reinterpret_cast<const s16x8*>(&h2l[off]);
            s16x8 y1h = *reinterpret_cast<const s16x8*>(&t1[off]);
            s16x8 y1l = *reinterpret_cast<const s16x8*>(&t1l[off]);
            s16x8 y2h = *reinterpret_cast<const s16x8*>(&t2[off]);
            s16x8 y2l = *reinterpret_cast<const s16x8*>(&t2l[off]);
            a1h[ti] = v ? x1h : z8; a1l[ti] = v ? x1l : z8;
            a2h[ti] = v ? x2h : z8; a2l[ti] = v ? x2l : z8;
            b1h[ti] = v ? y1h : z8; b1l[ti] = v ? y1l : z8;
            b2h[ti] = v ? y2h : z8; b2l[ti] = v ? y2l : z8;
        }
#pragma unroll
        for (int ti = 0; ti < TM; ++ti)
#pragma unroll
            for (int tj = 0; tj < TM; ++tj) {
                f32x4 c = acc[ti][tj];
                c = __builtin_amdgcn_mfma_f32_16x16x32_bf16(a1h[ti], b1h[tj], c, 0, 0, 0);
                c = __builtin_amdgcn_mfma_f32_16x16x32_bf16(a1h[ti], b1l[tj], c, 0, 0, 0);
                c = __builtin_amdgcn_mfma_f32_16x16x32_bf16(a1l[ti], b1h[tj], c, 0, 0, 0);
                c = __builtin_amdgcn_mfma_f32_16x16x32_bf16(a2h[ti], b2h[tj], c, 0, 0, 0);
                c = __builtin_amdgcn_mfma_f32_16x16x32_bf16(a2h[ti], b2l[tj], c, 0, 0, 0);
                c = __builtin_amdgcn_mfma_f32_16x16x32_bf16(a2l[ti], b2h[tj], c, 0, 0, 0);
                acc[ti][tj] = c;
            }
    }

    // alpha = tanh(acc). Padded entries are tanh(0)=0 -> contribute 0 to sums.
    float at[TM][TM][4];
#pragma unroll
    for (int ti = 0; ti < TM; ++ti)
#pragma unroll
        for (int tj = 0; tj < TM; ++tj)
#pragma unroll
            for (int r = 0; r < 4; ++r) at[ti][tj][r] = tanhf(acc[ti][tj][r]);

    constexpr float invR = 1.f / (float)R;

    // ---- col sums (over i) -> b_t, softmax over j, p_t ----
    float pc[TM];
#pragma unroll
    for (int tj = 0; tj < TM; ++tj) {
        float s = 0.f;
#pragma unroll
        for (int ti = 0; ti < TM; ++ti)
#pragma unroll
            for (int r = 0; r < 4; ++r) s += at[ti][tj][r];
        s += __shfl_xor(s, 16, 64);
        s += __shfl_xor(s, 32, 64);
        pc[tj] = s;
    }
    float bt[TM];
    bool vj[TM];
    float mx = -1e30f;
#pragma unroll
    for (int tj = 0; tj < TM; ++tj) {
        int j = tj * 16 + lm;
        vj[tj] = (j < R);
        bt[tj] = pc[tj] * invR;
        if (vj[tj]) mx = fmaxf(mx, bt[tj]);
    }
    mx = fmaxf(mx, __shfl_xor(mx, 1, 64));
    mx = fmaxf(mx, __shfl_xor(mx, 2, 64));
    mx = fmaxf(mx, __shfl_xor(mx, 4, 64));
    mx = fmaxf(mx, __shfl_xor(mx, 8, 64));
    float ev[TM];
    float es = 0.f;
#pragma unroll
    for (int tj = 0; tj < TM; ++tj) {
        ev[tj] = vj[tj] ? expf(bt[tj] - mx) : 0.f;
        es += ev[tj];
    }
    es += __shfl_xor(es, 1, 64);
    es += __shfl_xor(es, 2, 64);
    es += __shfl_xor(es, 4, 64);
    es += __shfl_xor(es, 8, 64);
    if (lq == 0) {
#pragma unroll
        for (int tj = 0; tj < TM; ++tj)
            if (vj[tj]) PT[tj * 16 + lm] = ev[tj] / es;
    }

    // ---- row sums (over j) -> b_h, softmax over i, p_h ----
    float bh[TM][4];
    float mh = -1e30f;
#pragma unroll
    for (int ti = 0; ti < TM; ++ti)
#pragma unroll
        for (int r = 0; r < 4; ++r) {
            float s = 0.f;
#pragma unroll
            for (int tj = 0; tj < TM; ++tj) s += at[ti][tj][r];
            s += __shfl_xor(s, 1, 64);
            s += __shfl_xor(s, 2, 64);
            s += __shfl_xor(s, 4, 64);
            s += __shfl_xor(s, 8, 64);
            bh[ti][r] = s * invR;
            int i = ti * 16 + lq * 4 + r;
            if (i < R) mh = fmaxf(mh, bh[ti][r]);
        }
    mh = fmaxf(mh, __shfl_xor(mh, 16, 64));
    mh = fmaxf(mh, __shfl_xor(mh, 32, 64));
    float eh[TM][4];
    float esh = 0.f;
#pragma unroll
    for (int ti = 0; ti < TM; ++ti)
#pragma unroll
        for (int r = 0; r < 4; ++r) {
            int i = ti * 16 + lq * 4 + r;
            eh[ti][r] = (i < R) ? expf(bh[ti][r] - mh) : 0.f;
            esh += eh[ti][r];
        }
    esh += __shfl_xor(esh, 16, 64);
    esh += __shfl_xor(esh, 32, 64);
    if (lm == 0) {
#pragma unroll
        for (int ti = 0; ti < TM; ++ti)
#pragma unroll
            for (int r = 0; r < 4; ++r) {
                int i = ti * 16 + lq * 4 + r;
                if (i < R) PH[i] = eh[ti][r] / esh;
            }
    }
    __syncthreads();

    // ---- outputs: s_t = sum_j p_t[j]*xt[j], s_h = sum_i p_h[i]*xh[i] ----
    float s0 = 0.f, s1 = 0.f, q0 = 0.f, q1 = 0.f;
    for (int j = 0; j < R; ++j) {
        float p = PT[j];
        const float* xr = xt + (base + j) * D;
        s0 += p * xr[l];
        s1 += p * xr[64 + l];
    }
    for (int i = 0; i < R; ++i) {
        float p = PH[i];
        const float* xr = xh + (base + i) * D;
        q0 += p * xr[l];
        q1 += p * xr[64 + l];
    }
    ost[g * D + l] = s0;
    ost[g * D + 64 + l] = s1;
    osh[g * D + l] = q0;
    osh[g * D + 64 + l] = q1;
}

__global__ __launch_bounds__(64) void attn_kernel(
    const float* __restrict__ xnh, const float* __restrict__ xnt,
    const float* __restrict__ xlh, const float* __restrict__ xlt,
    const unsigned short* __restrict__ wsu, float* __restrict__ out)
{
    __shared__ float PT[48], PH[48];
    int idx = blockIdx.x;
    if (idx < 256)
        attn_body<0>(idx, xnh, xnt, wsu, out + 0, out + 32768, PT, PH);
    else
        attn_body<1>(idx - 256, xlh, xlt, wsu, out + 65536, out + 98304, PT, PH);
}

extern "C" void kernel_launch(void* const* d_in, const int* in_sizes, int n_in,
                              void* d_out, int out_size, void* d_ws, size_t ws_size,
                              hipStream_t stream) {
    const float* xnh  = (const float*)d_in[0];
    const float* xnt  = (const float*)d_in[1];
    const float* xlh  = (const float*)d_in[2];
    const float* xlt  = (const float*)d_in[3];
    const float* Wh_w  = (const float*)d_in[4];
    const float* Wh_b  = (const float*)d_in[5];
    const float* Wt_w  = (const float*)d_in[6];
    const float* Wt_b  = (const float*)d_in[7];
    const float* Whl_w = (const float*)d_in[8];
    const float* Whl_b = (const float*)d_in[9];
    const float* Wtl_w = (const float*)d_in[10];
    const float* Wtl_b = (const float*)d_in[11];

    unsigned short* ws = (unsigned short*)d_ws;
    float* out = (float*)d_out;

    ProjArgs pa;
    // node level: xh1 = xnh@Wh^T+bh ; xh2 = xnh@Wt^T+bt ; xt1 = xnt@Wt^T+bt ; xt2 = xnt@Wh^T+bh
    pa.X[0] = xnh; pa.W[0] = Wh_w;  pa.Bv[0] = Wh_b;  pa.Yhi[0] = ws + 0;        pa.Ylo[0] = ws + 786432;
    pa.X[1] = xnh; pa.W[1] = Wt_w;  pa.Bv[1] = Wt_b;  pa.Yhi[1] = ws + 1572864;  pa.Ylo[1] = ws + 2359296;
    pa.X[2] = xnt; pa.W[2] = Wt_w;  pa.Bv[2] = Wt_b;  pa.Yhi[2] = ws + 3145728;  pa.Ylo[2] = ws + 3932160;
    pa.X[3] = xnt; pa.W[3] = Wh_w;  pa.Bv[3] = Wh_b;  pa.Yhi[3] = ws + 4718592;  pa.Ylo[3] = ws + 5505024;
    // line level
    pa.X[4] = xlh; pa.W[4] = Whl_w; pa.Bv[4] = Whl_b; pa.Yhi[4] = ws + 6291456;  pa.Ylo[4] = ws + 7602176;
    pa.X[5] = xlh; pa.W[5] = Wtl_w; pa.Bv[5] = Wtl_b; pa.Yhi[5] = ws + 8912896;  pa.Ylo[5] = ws + 10223616;
    pa.X[6] = xlt; pa.W[6] = Wtl_w; pa.Bv[6] = Wtl_b; pa.Yhi[6] = ws + 11534336; pa.Ylo[6] = ws + 12845056;
    pa.X[7] = xlt; pa.W[7] = Whl_w; pa.Bv[7] = Whl_b; pa.Yhi[7] = ws + 14155776; pa.Ylo[7] = ws + 15466496;

    proj_kernel<<<256, 512, 0, stream>>>(pa);
    attn_kernel<<<512, 64, 0, stream>>>(xnh, xnt, xlh, xlt, ws, out);
}